// Round 6
// baseline (79.070 us; speedup 1.0000x reference)
//
#include <hip/hip_runtime.h>
#include <cstdint>

// Problem: B=4, IC=OC=64, H=W=32, K=3, PAD=1
// Outputs: new_x (262144 f32), new_q (262144 f32) concatenated.
//
//   a0 = conv3x3(x,W,pad=1)+bias ; p0 = sigmoid(a0)
//   new_x = 2*(u < p0) - 1,  u = JAX threefry2x32-20, key=(0,42),
//           partitionable counter mode, draw = out0^out1   [verified r2]
//   new_q = 2*new_x*( s1*C1 - s2*C2 )   [2nd-order Taylor, err ~4e-5 << 2e-2]
//     s1 = p0(1-p0), s2 = s1(1-2p0),
//     C1 = conv3x3(x*q, W), C2 = conv3x3(q, W*W)
//
// Round 6: K-split main. 9 taps split 5/4 across wave pairs (i32 digit partials
// add EXACTLY -> a0 bit-identical); LDS exchange combines partials; epilogue
// rows split 2/2 per wave. 256 blocks x 512 thr = 2048 waves = 2 waves/SIMD
// (was 1 -> latency hiding doubled).
// Fragment layouts (16x16 family): A[m=lane&15][k=quad*(K/4)+j],
// B[k=quad*(K/4)+j][n=lane&15], C/D col(n)=lane&15, row(m)=quad*4+reg.

typedef __attribute__((ext_vector_type(4))) int   i32x4;
typedef __attribute__((ext_vector_type(8))) short s16x8;
typedef __attribute__((ext_vector_type(4))) float f32x4;

// ---- ws byte offsets ----
static constexpr int OFF_X8   = 0;          // i8  [b][34][34][64]   295,936 B
static constexpr int OFF_XQH  = 295936;     // bf16[b][34][34][64]   591,872 B
static constexpr int OFF_QH   = 887808;     // bf16[b][34][34][64]   591,872 B
static constexpr int OFF_WD   = 1479680;    // i8  [dig4][tap9][oc64][ic64] 147,456 B
static constexpr int OFF_WB   = 1627136;    // bf16[tap9][oc64][ic64] 73,728 B
static constexpr int OFF_W2B  = 1700864;    // bf16[tap9][oc64][ic64] 73,728 B
// total 1,774,592 B

__device__ __forceinline__ uint32_t rotl32(uint32_t v, int n) {
  return (v << n) | (v >> (32 - n));
}

__device__ __forceinline__ unsigned short f2bf(float f) {
  uint32_t u = __float_as_uint(f);
  uint32_t r = (u + 0x7FFFu + ((u >> 16) & 1u)) >> 16;   // RNE
  return (unsigned short)r;
}

// JAX threefry2x32-20, key=(0,42), partitionable: counter (0,j), draw=out0^out1
__device__ __forceinline__ float threefry_u(uint32_t j) {
  uint32_t x0 = 0u, x1 = j;
  const uint32_t ks1 = 42u, ks2 = 0x1BD11BDAu ^ 42u;
  x0 += 0u; x1 += ks1;
#define QR(rot) { x0 += x1; x1 = rotl32(x1, rot); x1 ^= x0; }
  QR(13) QR(15) QR(26) QR(6)
  x0 += ks1; x1 += ks2 + 1u;
  QR(17) QR(29) QR(16) QR(24)
  x0 += ks2; x1 += 0u + 2u;
  QR(13) QR(15) QR(26) QR(6)
  x0 += 0u; x1 += ks1 + 3u;
  QR(17) QR(29) QR(16) QR(24)
  x0 += ks1; x1 += ks2 + 4u;
  QR(13) QR(15) QR(26) QR(6)
  x0 += ks2; x1 += 0u + 5u;
#undef QR
  uint32_t bits = x0 ^ x1;
  return __uint_as_float((bits >> 9) | 0x3F800000u) - 1.0f;
}

// ---------------- prep (unchanged from r5: coalesced) -------------------------------
__global__ __launch_bounds__(256) void prep_kernel(
    const float* __restrict__ x, const float* __restrict__ q,
    const float* __restrict__ weight, char* __restrict__ ws) {
  const int blk = blockIdx.x;
  const int tid = threadIdx.x;

  if (blk < 128) {
    const int b = blk >> 5;
    const int h = blk & 31;
    __shared__ char           x8s[2048];   // [w][ic]
    __shared__ unsigned short xqs[2048];
    __shared__ unsigned short qs [2048];
    const int ic = tid >> 2;
    const int w0 = (tid & 3) * 8;
    const int src = ((b * 64 + ic) * 32 + h) * 32 + w0;
    float4 xa = *(const float4*)(x + src);
    float4 xb = *(const float4*)(x + src + 4);
    float4 qa = *(const float4*)(q + src);
    float4 qb = *(const float4*)(q + src + 4);
    float xv[8] = {xa.x, xa.y, xa.z, xa.w, xb.x, xb.y, xb.z, xb.w};
    float qv[8] = {qa.x, qa.y, qa.z, qa.w, qb.x, qb.y, qb.z, qb.w};
#pragma unroll
    for (int j = 0; j < 8; ++j) {
      int a = (w0 + j) * 64 + ic;
      x8s[a] = (char)(int)xv[j];
      xqs[a] = f2bf(xv[j] * qv[j]);
      qs[a]  = f2bf(qv[j]);
    }
    __syncthreads();
    const int rowel = ((b * 34 + h + 1) * 34 + 1) * 64;
    ((uint2*)(ws + OFF_X8 + rowel))[tid]      = ((const uint2*)x8s)[tid];
    ((uint4*)(ws + OFF_XQH + rowel * 2))[tid] = ((const uint4*)xqs)[tid];
    ((uint4*)(ws + OFF_QH  + rowel * 2))[tid] = ((const uint4*)qs)[tid];
  } else if (blk < 132) {
    const int b = blk - 128;
    for (int k = tid; k < 8448; k += 256) {
      int cell = k >> 6;
      int ic = k & 63;
      int hp, wp;
      if (cell < 34)       { hp = 0;          wp = cell; }
      else if (cell < 68)  { hp = 33;         wp = cell - 34; }
      else if (cell < 100) { hp = cell - 67;  wp = 0; }
      else                 { hp = cell - 99;  wp = 33; }
      int a = ((b * 34 + hp) * 34 + wp) * 64 + ic;
      ((char*)(ws + OFF_X8))[a] = 0;
      ((unsigned short*)(ws + OFF_XQH))[a] = 0;
      ((unsigned short*)(ws + OFF_QH))[a]  = 0;
    }
  } else {
    int k  = (blk - 132) * 256 + tid;      // < 36864, k = tap*4096 + oc*64 + ic
    int ic = k & 63;
    int t  = k >> 6;
    int oc  = t & 63;
    int tap = t >> 6;
    int kh = tap / 3, kw = tap % 3;
    float Wv = weight[((oc * 64 + ic) * 3 + kh) * 3 + kw];
    long long wi = llrint((double)Wv * 2147483648.0);
    char* wd = ws + OFF_WD;
#pragma unroll
    for (int dig = 0; dig < 4; ++dig) {
      signed char d = (signed char)(wi & 0xFF);
      wd[dig * 36864 + k] = d;
      wi = (wi - (long long)d) >> 8;
    }
    ((unsigned short*)(ws + OFF_WB))[k]  = f2bf(Wv);
    ((unsigned short*)(ws + OFF_W2B))[k] = f2bf(Wv * Wv);
  }
}

// ---------------- main: K-split MFMA + LDS combine + split epilogue -----------------
// grid 256 = (b*32+h)*2+nt ; block 512 = 8 waves: (half, octile)
__global__ __launch_bounds__(512) void main_kernel(
    const char* __restrict__ ws, const float* __restrict__ bias,
    float* __restrict__ out) {
  const char* x8            = ws + OFF_X8;
  const unsigned short* xqh = (const unsigned short*)(ws + OFF_XQH);
  const unsigned short* qh  = (const unsigned short*)(ws + OFF_QH);
  const char* wd            = ws + OFF_WD;
  const unsigned short* wb  = (const unsigned short*)(ws + OFF_WB);
  const unsigned short* w2b = (const unsigned short*)(ws + OFF_W2B);

  __shared__ int lds[4 * 2 * 12 * 64];   // [octile][writerHalf][slot][lane] 24 KB

  const int b  = blockIdx.x >> 6;
  const int h  = (blockIdx.x >> 1) & 31;
  const int nt = blockIdx.x & 1;

  const int tid    = threadIdx.x;
  const int octile = (tid >> 6) & 3;
  const int half   = tid >> 8;          // 0: taps 0-4, 1: taps 5-8
  const int lane   = tid & 63;
  const int quad   = lane >> 4;
  const int l16    = lane & 15;

  i32x4 accI[4];
#pragma unroll
  for (int d = 0; d < 4; ++d) accI[d] = (i32x4){0, 0, 0, 0};
  f32x4 aC1 = {0.f, 0.f, 0.f, 0.f};
  f32x4 aC2 = {0.f, 0.f, 0.f, 0.f};

  const int aoff_i8 = (octile * 16 + l16) * 64 + quad * 16;   // bytes
  const int aoff_bf = (octile * 16 + l16) * 64 + quad * 8;    // ushort elems

  const int tbase = half ? 5 : 0;
  const int tnum  = half ? 4 : 5;
#pragma unroll
  for (int i = 0; i < 5; ++i) {
    if (i < tnum) {                       // wave-uniform guard
      const int tap = tbase + i;
      const int kh = tap / 3;
      const int kw = tap - kh * 3;
      i32x4 aI[4];
#pragma unroll
      for (int d = 0; d < 4; ++d)
        aI[d] = *(const i32x4*)(wd + d * 36864 + tap * 4096 + aoff_i8);
      s16x8 aW0 = *(const s16x8*)(wb  + tap * 4096 + aoff_bf);
      s16x8 aW1 = *(const s16x8*)(wb  + tap * 4096 + aoff_bf + 32);
      s16x8 aV0 = *(const s16x8*)(w2b + tap * 4096 + aoff_bf);
      s16x8 aV1 = *(const s16x8*)(w2b + tap * 4096 + aoff_bf + 32);
      const int pix = ((b * 34 + h + kh) * 34 + (nt * 16 + l16 + kw)) * 64;
      i32x4 bI  = *(const i32x4*)(x8 + pix + quad * 16);
      s16x8 bX0 = *(const s16x8*)(xqh + pix + quad * 8);
      s16x8 bX1 = *(const s16x8*)(xqh + pix + 32 + quad * 8);
      s16x8 bQ0 = *(const s16x8*)(qh  + pix + quad * 8);
      s16x8 bQ1 = *(const s16x8*)(qh  + pix + 32 + quad * 8);
#pragma unroll
      for (int d = 0; d < 4; ++d)
        accI[d] = __builtin_amdgcn_mfma_i32_16x16x64_i8(aI[d], bI, accI[d], 0, 0, 0);
      aC1 = __builtin_amdgcn_mfma_f32_16x16x32_bf16(aW0, bX0, aC1, 0, 0, 0);
      aC1 = __builtin_amdgcn_mfma_f32_16x16x32_bf16(aW1, bX1, aC1, 0, 0, 0);
      aC2 = __builtin_amdgcn_mfma_f32_16x16x32_bf16(aV0, bQ0, aC2, 0, 0, 0);
      aC2 = __builtin_amdgcn_mfma_f32_16x16x32_bf16(aV1, bQ1, aC2, 0, 0, 0);
    }
  }

  // ---- exchange: write partials for PARTNER's row-subset, read partner's ----
  // subsets: half0 owns rows r=0,1 ; half1 owns rows r=2,3 (rows within quad)
  {
    const int rp = 2 * (1 - half);      // partner's first row
    int* wr = lds + ((octile * 2 + half) * 12) * 64 + lane;
#pragma unroll
    for (int d = 0; d < 4; ++d) {
      wr[(d) * 64]     = accI[d][rp];
      wr[(4 + d) * 64] = accI[d][rp + 1];
    }
    wr[8 * 64]  = __float_as_int(aC1[rp]);
    wr[9 * 64]  = __float_as_int(aC1[rp + 1]);
    wr[10 * 64] = __float_as_int(aC2[rp]);
    wr[11 * 64] = __float_as_int(aC2[rp + 1]);
  }
  __syncthreads();
  const int r0 = 2 * half;              // my first row
  {
    const int* rd = lds + ((octile * 2 + (1 - half)) * 12) * 64 + lane;
#pragma unroll
    for (int d = 0; d < 4; ++d) {
      accI[d][r0]     += rd[(d) * 64];
      accI[d][r0 + 1] += rd[(4 + d) * 64];
    }
    aC1[r0]     += __int_as_float(rd[8 * 64]);
    aC1[r0 + 1] += __int_as_float(rd[9 * 64]);
    aC2[r0]     += __int_as_float(rd[10 * 64]);
    aC2[r0 + 1] += __int_as_float(rd[11 * 64]);
  }

  // ---- epilogue: 2 rows per wave. C/D col(n=px)=l16, row(m=oc)=quad*4+r ----
  const int w = nt * 16 + l16;
#pragma unroll
  for (int rr = 0; rr < 2; ++rr) {
    const int r = r0 + rr;
    const int ocr = octile * 16 + quad * 4 + r;
    double a0 = (((double)accI[3][r] * 256.0 + (double)accI[2][r]) * 256.0 +
                 (double)accI[1][r]) * 256.0 + (double)accI[0][r];
    a0 = a0 * (1.0 / 2147483648.0) + (double)bias[ocr];
    double p0d = 1.0 / (1.0 + exp(-a0));
    const int o = ((b * 64 + ocr) * 32 + h) * 32 + w;
    float su = threefry_u((uint32_t)o);
    float nx = ((double)su < p0d) ? 1.0f : -1.0f;
    float p0 = (float)p0d;
    float s1 = p0 * (1.0f - p0);
    float s2 = s1 * (1.0f - 2.0f * p0);
    float dq = 2.0f * nx * (s1 * aC1[r] - s2 * aC2[r]);
    out[o] = nx;
    out[262144 + o] = dq;
  }
}

extern "C" void kernel_launch(void* const* d_in, const int* in_sizes, int n_in,
                              void* d_out, int out_size, void* d_ws, size_t ws_size,
                              hipStream_t stream) {
  const float* x      = (const float*)d_in[0];
  const float* q      = (const float*)d_in[1];
  const float* weight = (const float*)d_in[2];
  const float* bias   = (const float*)d_in[3];
  float* out = (float*)d_out;
  char* ws   = (char*)d_ws;

  // prep: 128 row blocks + 4 border blocks + 144 weight blocks = 276
  prep_kernel<<<276, 256, 0, stream>>>(x, q, weight, ws);
  // main: 256 blocks x 512 threads (8 waves: 4 octiles x 2 K-halves)
  main_kernel<<<256, 512, 0, stream>>>(ws, bias, out);
}

// Round 7
// 72.471 us; speedup vs baseline: 1.0911x; 1.0911x over previous
//
#include <hip/hip_runtime.h>
#include <cstdint>

// Problem: B=4, IC=OC=64, H=W=32, K=3, PAD=1
// Outputs: new_x (262144 f32), new_q (262144 f32) concatenated.
//
//   a0 = conv3x3(x,W,pad=1)+bias ; p0 = sigmoid(a0)
//   new_x = 2*(u < p0) - 1,  u = JAX threefry2x32-20, key=(0,42),
//           partitionable counter mode, draw = out0^out1   [verified r2]
//   new_q = 2*new_x*s1*C1   [1st-order Taylor in delta=2xW; dropped 2nd-order
//           s2*C2 term is bounded by 6e-7 << 2e-2 threshold: C2=sum q*W^2 <=
//           576*0.001*0.0052 = 3e-6, |s2|<=0.1]
//     s1 = p0(1-p0),  C1 = conv3x3(x*q, W)
//
// Round 7: round-5 structure (best: 75.3us) minus the C2/qh/w2b path.
// a0 stays EXACT: W split into 4 signed radix-256 digits of round(W*2^31),
// x as i8, mfma_i32_16x16x64_i8 (i32 accum exact), f64 reconstruction +
// f64 sigmoid -> bit-stable vs np-f64 reference (verified rounds 2-6).
// Fragment layouts (16x16 family): A[m=lane&15][k=quad*(K/4)+j],
// B[k=quad*(K/4)+j][n=lane&15], C/D col(n)=lane&15, row(m)=quad*4+reg.

typedef __attribute__((ext_vector_type(4))) int   i32x4;
typedef __attribute__((ext_vector_type(8))) short s16x8;
typedef __attribute__((ext_vector_type(4))) float f32x4;

// ---- ws byte offsets ----
static constexpr int OFF_X8   = 0;          // i8  [b][34][34][64]   295,936 B
static constexpr int OFF_XQH  = 295936;     // bf16[b][34][34][64]   591,872 B
static constexpr int OFF_WD   = 887808;     // i8  [dig4][tap9][oc64][ic64] 147,456 B
static constexpr int OFF_WB   = 1035264;    // bf16[tap9][oc64][ic64] 73,728 B
// total 1,108,992 B

__device__ __forceinline__ uint32_t rotl32(uint32_t v, int n) {
  return (v << n) | (v >> (32 - n));
}

__device__ __forceinline__ unsigned short f2bf(float f) {
  uint32_t u = __float_as_uint(f);
  uint32_t r = (u + 0x7FFFu + ((u >> 16) & 1u)) >> 16;   // RNE
  return (unsigned short)r;
}

// JAX threefry2x32-20, key=(0,42), partitionable: counter (0,j), draw=out0^out1
__device__ __forceinline__ float threefry_u(uint32_t j) {
  uint32_t x0 = 0u, x1 = j;
  const uint32_t ks1 = 42u, ks2 = 0x1BD11BDAu ^ 42u;
  x0 += 0u; x1 += ks1;
#define QR(rot) { x0 += x1; x1 = rotl32(x1, rot); x1 ^= x0; }
  QR(13) QR(15) QR(26) QR(6)
  x0 += ks1; x1 += ks2 + 1u;
  QR(17) QR(29) QR(16) QR(24)
  x0 += ks2; x1 += 0u + 2u;
  QR(13) QR(15) QR(26) QR(6)
  x0 += 0u; x1 += ks1 + 3u;
  QR(17) QR(29) QR(16) QR(24)
  x0 += ks1; x1 += ks2 + 4u;
  QR(13) QR(15) QR(26) QR(6)
  x0 += ks2; x1 += 0u + 5u;
#undef QR
  uint32_t bits = x0 ^ x1;
  return __uint_as_float((bits >> 9) | 0x3F800000u) - 1.0f;
}

// ---------------- prep ---------------------------------------------------------------
// blocks 0..127   : interior row (b=blk>>5, h=blk&31), coalesced read -> LDS
//                   transpose -> contiguous row write (x8, xqh)
// blocks 128..131 : border zeros for b = blk-128
// blocks 132..275 : weight digitization + bf16 table
__global__ __launch_bounds__(256) void prep_kernel(
    const float* __restrict__ x, const float* __restrict__ q,
    const float* __restrict__ weight, char* __restrict__ ws) {
  const int blk = blockIdx.x;
  const int tid = threadIdx.x;

  if (blk < 128) {
    const int b = blk >> 5;
    const int h = blk & 31;
    __shared__ char           x8s[2048];   // [w][ic]
    __shared__ unsigned short xqs[2048];
    const int ic = tid >> 2;
    const int w0 = (tid & 3) * 8;
    const int src = ((b * 64 + ic) * 32 + h) * 32 + w0;
    float4 xa = *(const float4*)(x + src);
    float4 xb = *(const float4*)(x + src + 4);
    float4 qa = *(const float4*)(q + src);
    float4 qb = *(const float4*)(q + src + 4);
    float xv[8] = {xa.x, xa.y, xa.z, xa.w, xb.x, xb.y, xb.z, xb.w};
    float qv[8] = {qa.x, qa.y, qa.z, qa.w, qb.x, qb.y, qb.z, qb.w};
#pragma unroll
    for (int j = 0; j < 8; ++j) {
      int a = (w0 + j) * 64 + ic;
      x8s[a] = (char)(int)xv[j];
      xqs[a] = f2bf(xv[j] * qv[j]);
    }
    __syncthreads();
    // dest row [b][h+1][1..32][ic]: 2048 contiguous elements
    const int rowel = ((b * 34 + h + 1) * 34 + 1) * 64;
    ((uint2*)(ws + OFF_X8 + rowel))[tid]      = ((const uint2*)x8s)[tid];
    ((uint4*)(ws + OFF_XQH + rowel * 2))[tid] = ((const uint4*)xqs)[tid];
  } else if (blk < 132) {
    const int b = blk - 128;
    // 132 border cells x 64 ic = 8448 elements
    for (int k = tid; k < 8448; k += 256) {
      int cell = k >> 6;
      int ic = k & 63;
      int hp, wp;
      if (cell < 34)       { hp = 0;          wp = cell; }
      else if (cell < 68)  { hp = 33;         wp = cell - 34; }
      else if (cell < 100) { hp = cell - 67;  wp = 0; }       // 1..32
      else                 { hp = cell - 99;  wp = 33; }      // 1..32
      int a = ((b * 34 + hp) * 34 + wp) * 64 + ic;
      ((char*)(ws + OFF_X8))[a] = 0;
      ((unsigned short*)(ws + OFF_XQH))[a] = 0;
    }
  } else {
    // weights: k = tap*4096 + oc*64 + ic
    int k  = (blk - 132) * 256 + tid;      // < 36864
    int ic = k & 63;
    int t  = k >> 6;
    int oc  = t & 63;
    int tap = t >> 6;
    int kh = tap / 3, kw = tap % 3;
    float Wv = weight[((oc * 64 + ic) * 3 + kh) * 3 + kw];
    long long wi = llrint((double)Wv * 2147483648.0);   // round(W*2^31), |wi|<2^28
    char* wd = ws + OFF_WD;
#pragma unroll
    for (int dig = 0; dig < 4; ++dig) {
      signed char d = (signed char)(wi & 0xFF);          // balanced low byte
      wd[dig * 36864 + k] = d;
      wi = (wi - (long long)d) >> 8;
    }
    ((unsigned short*)(ws + OFF_WB))[k]  = f2bf(Wv);
  }
}

// ---------------- main: MFMA convs + f64 sigmoid + inline threefry ------------------
// grid 256 = (b*32 + h)*2 + nt ; block 256 = 4 waves, wave = oc-tile (16 oc)
__global__ __launch_bounds__(256) void main_kernel(
    const char* __restrict__ ws, const float* __restrict__ bias,
    float* __restrict__ out) {
  const char* x8            = ws + OFF_X8;
  const unsigned short* xqh = (const unsigned short*)(ws + OFF_XQH);
  const char* wd            = ws + OFF_WD;
  const unsigned short* wb  = (const unsigned short*)(ws + OFF_WB);

  const int b  = blockIdx.x >> 6;
  const int h  = (blockIdx.x >> 1) & 31;
  const int nt = blockIdx.x & 1;

  const int octile = threadIdx.x >> 6;
  const int lane   = threadIdx.x & 63;
  const int quad   = lane >> 4;
  const int l16    = lane & 15;

  i32x4 accI[4];
#pragma unroll
  for (int d = 0; d < 4; ++d) accI[d] = (i32x4){0, 0, 0, 0};
  f32x4 aC1 = {0.f, 0.f, 0.f, 0.f};

  const int aoff_i8 = (octile * 16 + l16) * 64 + quad * 16;   // bytes
  const int aoff_bf = (octile * 16 + l16) * 64 + quad * 8;    // ushort elems

#pragma unroll
  for (int kh = 0; kh < 3; ++kh) {
#pragma unroll
    for (int kw = 0; kw < 3; ++kw) {
      const int tap = kh * 3 + kw;
      i32x4 aI[4];
#pragma unroll
      for (int d = 0; d < 4; ++d)
        aI[d] = *(const i32x4*)(wd + d * 36864 + tap * 4096 + aoff_i8);
      s16x8 aW0 = *(const s16x8*)(wb + tap * 4096 + aoff_bf);
      s16x8 aW1 = *(const s16x8*)(wb + tap * 4096 + aoff_bf + 32);
      const int pix = ((b * 34 + h + kh) * 34 + (nt * 16 + l16 + kw)) * 64;
      i32x4 bI  = *(const i32x4*)(x8 + pix + quad * 16);
      s16x8 bX0 = *(const s16x8*)(xqh + pix + quad * 8);
      s16x8 bX1 = *(const s16x8*)(xqh + pix + 32 + quad * 8);
#pragma unroll
      for (int d = 0; d < 4; ++d)
        accI[d] = __builtin_amdgcn_mfma_i32_16x16x64_i8(aI[d], bI, accI[d], 0, 0, 0);
      aC1 = __builtin_amdgcn_mfma_f32_16x16x32_bf16(aW0, bX0, aC1, 0, 0, 0);
      aC1 = __builtin_amdgcn_mfma_f32_16x16x32_bf16(aW1, bX1, aC1, 0, 0, 0);
    }
  }

  // ---- epilogue: C/D col(n=px)=l16, row(m=oc)=quad*4+r ----
  const int w = nt * 16 + l16;
#pragma unroll
  for (int r = 0; r < 4; ++r) {
    const int ocr = octile * 16 + quad * 4 + r;
    double a0 = (((double)accI[3][r] * 256.0 + (double)accI[2][r]) * 256.0 +
                 (double)accI[1][r]) * 256.0 + (double)accI[0][r];
    a0 = a0 * (1.0 / 2147483648.0) + (double)bias[ocr];
    double p0d = 1.0 / (1.0 + exp(-a0));
    const int o = ((b * 64 + ocr) * 32 + h) * 32 + w;
    float su = threefry_u((uint32_t)o);
    float nx = ((double)su < p0d) ? 1.0f : -1.0f;
    float p0 = (float)p0d;
    float s1 = p0 * (1.0f - p0);
    float dq = 2.0f * nx * s1 * aC1[r];
    out[o] = nx;
    out[262144 + o] = dq;
  }
}

extern "C" void kernel_launch(void* const* d_in, const int* in_sizes, int n_in,
                              void* d_out, int out_size, void* d_ws, size_t ws_size,
                              hipStream_t stream) {
  const float* x      = (const float*)d_in[0];
  const float* q      = (const float*)d_in[1];
  const float* weight = (const float*)d_in[2];
  const float* bias   = (const float*)d_in[3];
  float* out = (float*)d_out;
  char* ws   = (char*)d_ws;

  // prep: 128 row blocks + 4 border blocks + 144 weight blocks = 276
  prep_kernel<<<276, 256, 0, stream>>>(x, q, weight, ws);
  // main: (b*32+h)*2+nt = 256 blocks, 4 waves each (oc-tiles)
  main_kernel<<<256, 256, 0, stream>>>(ws, bias, out);
}